// Round 4
// baseline (5450.978 us; speedup 1.0000x reference)
//
#include <hip/hip_runtime.h>
#include <math.h>

#define NN 500000
#define NE 16000000
#define ST 62                    // supertiles: dst>>13 (8192 dst nodes each)
#define STB 8192
#define NG 489                   // src groups: src>>10 (1024 srcs = 4KB z window)
#define PBA 16384                // edges per phase-A block
#define NBA ((NE/4 + PBA/4 - 1) / (PBA/4))   // 977 blocks (int4 loads)
#define SUBB 16                  // phase-B blocks per supertile
#define NBB (ST * SUBB)          // 992
#define CHUNKS 16                // accumulate blocks per supertile
#define NBACC (ST * CHUNKS)      // 992

// ---------- phase A1: histogram by supertile ----------
__global__ __launch_bounds__(256) void histA(const int4* __restrict__ dst4,
                                             int* __restrict__ bcntA) {
    __shared__ int lh[ST];
    if (threadIdx.x < ST) lh[threadIdx.x] = 0;
    __syncthreads();
    long base4 = (long)blockIdx.x * (PBA / 4);
    for (int k = 0; k < PBA / 4; k += 256) {
        long i4 = base4 + k + threadIdx.x;
        if (i4 < NE / 4) {
            int4 d = dst4[i4];
            atomicAdd(&lh[d.x >> 13], 1);
            atomicAdd(&lh[d.y >> 13], 1);
            atomicAdd(&lh[d.z >> 13], 1);
            atomicAdd(&lh[d.w >> 13], 1);
        }
    }
    __syncthreads();
    if (threadIdx.x < ST) {
        int c = lh[threadIdx.x];
        if (c) atomicAdd(&bcntA[threadIdx.x], c);
    }
}

// ---------- phase A2: scan 62 counts (one wave) ----------
__global__ void scanA(const int* __restrict__ bcntA, int* __restrict__ regBase,
                      int* __restrict__ curA) {
    int i = threadIdx.x;                          // 64 threads
    int v = (i < ST) ? bcntA[i] : 0;
    int incl = v;
    for (int off = 1; off < 64; off <<= 1) {
        int t = __shfl_up(incl, off);
        if (i >= off) incl += t;
    }
    if (i < ST) { regBase[i] = incl - v; curA[i] = incl - v; }
    if (i == 63) regBase[ST] = incl;
}

// ---------- phase A3: scatter into supertile regions, packed ----------
// tmp[pos] = (dst&8191)<<19 | src   (uint32, fills exactly)
__global__ __launch_bounds__(256) void scatterA(const int4* __restrict__ src4,
                                                const int4* __restrict__ dst4,
                                                int* __restrict__ curA,
                                                unsigned* __restrict__ tmp) {
    __shared__ int lh[ST];
    if (threadIdx.x < ST) lh[threadIdx.x] = 0;
    __syncthreads();
    long base4 = (long)blockIdx.x * (PBA / 4);
    for (int k = 0; k < PBA / 4; k += 256) {
        long i4 = base4 + k + threadIdx.x;
        if (i4 < NE / 4) {
            int4 d = dst4[i4];
            atomicAdd(&lh[d.x >> 13], 1);
            atomicAdd(&lh[d.y >> 13], 1);
            atomicAdd(&lh[d.z >> 13], 1);
            atomicAdd(&lh[d.w >> 13], 1);
        }
    }
    __syncthreads();
    if (threadIdx.x < ST) {
        int c = lh[threadIdx.x];
        if (c) lh[threadIdx.x] = atomicAdd(&curA[threadIdx.x], c);
    }
    __syncthreads();
    for (int k = 0; k < PBA / 4; k += 256) {
        long i4 = base4 + k + threadIdx.x;
        if (i4 < NE / 4) {
            int4 d = dst4[i4];
            int4 s = src4[i4];
            int p;
            p = atomicAdd(&lh[d.x >> 13], 1); tmp[p] = ((unsigned)(d.x & 8191) << 19) | (unsigned)s.x;
            p = atomicAdd(&lh[d.y >> 13], 1); tmp[p] = ((unsigned)(d.y & 8191) << 19) | (unsigned)s.y;
            p = atomicAdd(&lh[d.z >> 13], 1); tmp[p] = ((unsigned)(d.z & 8191) << 19) | (unsigned)s.z;
            p = atomicAdd(&lh[d.w >> 13], 1); tmp[p] = ((unsigned)(d.w & 8191) << 19) | (unsigned)s.w;
        }
    }
}

// ---------- phase B1: per-cell (supertile, src-group) histogram + node degree ----------
__global__ __launch_bounds__(256) void histB(const unsigned* __restrict__ tmp,
                                             const int* __restrict__ regBase,
                                             int* __restrict__ cellCnt,
                                             int* __restrict__ deg) {
    __shared__ int gh[NG];
    __shared__ int dh[STB];
    int st = blockIdx.x >> 4, sb = blockIdx.x & 15;
    int base = regBase[st];
    int len = regBase[st + 1] - base;
    int beg = base + (int)((long)len * sb / SUBB);
    int end = base + (int)((long)len * (sb + 1) / SUBB);
    for (int i = threadIdx.x; i < NG; i += 256) gh[i] = 0;
    for (int i = threadIdx.x; i < STB; i += 256) dh[i] = 0;
    __syncthreads();
    for (int i = beg + threadIdx.x; i < end; i += 256) {
        unsigned e = tmp[i];
        atomicAdd(&gh[(e & 0x7FFFFu) >> 10], 1);
        atomicAdd(&dh[e >> 19], 1);
    }
    __syncthreads();
    for (int i = threadIdx.x; i < NG; i += 256) {
        int c = gh[i];
        if (c) atomicAdd(&cellCnt[st * NG + i], c);
    }
    for (int i = threadIdx.x; i < STB; i += 256) {
        int c = dh[i];
        if (c) atomicAdd(&deg[st * STB + i], c);
    }
}

// ---------- phase B2: per-supertile exclusive scan of 489 cell counts ----------
__global__ __launch_bounds__(256) void scanB(const int* __restrict__ regBase,
                                             const int* __restrict__ cellCnt,
                                             int* __restrict__ cellCur) {
    __shared__ int sh[256];
    __shared__ int carry_sh;
    int st = blockIdx.x;
    if (threadIdx.x == 0) carry_sh = regBase[st];
    __syncthreads();
    for (int base = 0; base < NG; base += 256) {
        int i = base + threadIdx.x;
        int v = (i < NG) ? cellCnt[st * NG + i] : 0;
        sh[threadIdx.x] = v;
        __syncthreads();
        for (int off = 1; off < 256; off <<= 1) {
            int t = (threadIdx.x >= off) ? sh[threadIdx.x - off] : 0;
            __syncthreads();
            sh[threadIdx.x] += t;
            __syncthreads();
        }
        int incl = sh[threadIdx.x];
        int c = carry_sh;
        __syncthreads();
        if (i < NG) cellCur[st * NG + i] = c + incl - v;
        if (threadIdx.x == 255) carry_sh = c + incl;
        __syncthreads();
    }
}

// ---------- phase B3: scatter within supertile by src-group ----------
__global__ __launch_bounds__(256) void scatterB(const unsigned* __restrict__ tmp,
                                                const int* __restrict__ regBase,
                                                int* __restrict__ cellCur,
                                                unsigned* __restrict__ ebuf) {
    __shared__ int gh[NG];
    int st = blockIdx.x >> 4, sb = blockIdx.x & 15;
    int base = regBase[st];
    int len = regBase[st + 1] - base;
    int beg = base + (int)((long)len * sb / SUBB);
    int end = base + (int)((long)len * (sb + 1) / SUBB);
    for (int i = threadIdx.x; i < NG; i += 256) gh[i] = 0;
    __syncthreads();
    for (int i = beg + threadIdx.x; i < end; i += 256)
        atomicAdd(&gh[(tmp[i] & 0x7FFFFu) >> 10], 1);
    __syncthreads();
    for (int i = threadIdx.x; i < NG; i += 256) {
        int c = gh[i];
        if (c) gh[i] = atomicAdd(&cellCur[st * NG + i], c);
    }
    __syncthreads();
    for (int i = beg + threadIdx.x; i < end; i += 256) {
        unsigned e = tmp[i];
        int pos = atomicAdd(&gh[(e & 0x7FFFFu) >> 10], 1);
        ebuf[pos] = e;
    }
}

// ---------- dis + z0 ----------
__global__ void disz(const int* __restrict__ deg, const float* __restrict__ x0,
                     float* __restrict__ dis, float* __restrict__ z0) {
    int v = blockIdx.x * 256 + threadIdx.x;
    if (v < NN) {
        float f = rsqrtf((float)(deg[v] + 1));     // +1 self loop
        dis[v] = f;
        z0[v] = x0[v] * f;
    }
}

// ---------- per-layer: accumulate (src-grouped gather -> LDS tile -> global) ----------
__global__ __launch_bounds__(512) void accum(const unsigned* __restrict__ ebuf,
                                             const int* __restrict__ regBase,
                                             const float* __restrict__ zin,
                                             float* __restrict__ hglob) {
    __shared__ float h[STB];
    int st = blockIdx.x >> 4, c = blockIdx.x & 15;
    int base = regBase[st];
    int len = regBase[st + 1] - base;
    int beg = base + (int)((long)len * c / CHUNKS);
    int end = base + (int)((long)len * (c + 1) / CHUNKS);
    for (int j = threadIdx.x; j < STB; j += 512) h[j] = 0.f;
    __syncthreads();
    #pragma unroll 4
    for (int i = beg + threadIdx.x; i < end; i += 512) {
        unsigned e = ebuf[i];
        atomicAdd(&h[e >> 19], zin[e & 0x7FFFFu]);
    }
    __syncthreads();
    for (int j = threadIdx.x; j < STB; j += 512) {
        float v = h[j];
        if (v != 0.f) atomicAdd(&hglob[st * STB + j], v);
    }
}

// ---------- per-layer: finalize (self-loop, combine, activation), re-zero hglob ----------
// act: 0=none 1=relu 2=leaky(0.01) 3=sigmoid 4=final(n*sigmoid -> int)
__global__ __launch_bounds__(256) void finalize(float* __restrict__ hglob,
                                                const float* __restrict__ zin,
                                                const float* __restrict__ dis,
                                                const float* __restrict__ x0,
                                                const float* __restrict__ w,
                                                int li, int act,
                                                float* __restrict__ zout,
                                                int* __restrict__ out) {
    int v = blockIdx.x * 256 + threadIdx.x;
    if (v >= NN) return;
    float hv = hglob[v];
    hglob[v] = 0.f;                                 // ready for next layer
    float s = hv + zin[v];                          // + self loop
    float hh = dis[v] * s;
    float comb = 0.7f * hh + 0.3f * x0[v];
    float y = comb * w[li];
    if (act == 4) {
        float sg = 1.f / (1.f + expf(-y));
        out[v] = (int)(500000.f * sg);
        return;
    }
    float r;
    if (act == 0)      r = y;
    else if (act == 1) r = fmaxf(y, 0.f);
    else if (act == 2) r = (y > 0.f) ? y : 0.01f * y;
    else               r = 1.f / (1.f + expf(-y));  // sigmoid
    zout[v] = dis[v] * r;
}

// ---------- launch ----------
extern "C" void kernel_launch(void* const* d_in, const int* in_sizes, int n_in,
                              void* d_out, int out_size, void* d_ws, size_t ws_size,
                              hipStream_t stream) {
    const float* x0  = (const float*)d_in[0];
    const float* w   = (const float*)d_in[1];
    const int*   adj = (const int*)d_in[2];          // int32 (jax demotes int64)
    const int*   src = adj;
    const int*   dst = adj + NE;
    int* out = (int*)d_out;

    uintptr_t p = (uintptr_t)d_ws;
    auto alloc = [&](size_t bytes) -> void* {
        p = (p + 255) & ~(uintptr_t)255;
        void* r = (void*)p;
        p += bytes;
        return r;
    };
    float*    dis     = (float*)alloc((size_t)NN * 4);
    float*    z0      = (float*)alloc((size_t)NN * 4);
    float*    z1      = (float*)alloc((size_t)NN * 4);
    int*      deg     = (int*)alloc((size_t)NN * 4);
    float*    hglob   = (float*)alloc((size_t)ST * STB * 4);
    int*      bcntA   = (int*)alloc((size_t)ST * 4);
    int*      regBase = (int*)alloc((size_t)(ST + 1) * 4);
    int*      curA    = (int*)alloc((size_t)ST * 4);
    int*      cellCnt = (int*)alloc((size_t)ST * NG * 4);
    int*      cellCur = (int*)alloc((size_t)ST * NG * 4);
    unsigned* tmp     = (unsigned*)alloc((size_t)NE * 4);
    unsigned* ebuf    = (unsigned*)alloc((size_t)NE * 4);
    (void)ws_size;

    hipMemsetAsync(bcntA, 0, (size_t)ST * 4, stream);
    hipMemsetAsync(cellCnt, 0, (size_t)ST * NG * 4, stream);
    hipMemsetAsync(deg, 0, (size_t)NN * 4, stream);
    hipMemsetAsync(hglob, 0, (size_t)ST * STB * 4, stream);

    histA<<<NBA, 256, 0, stream>>>((const int4*)dst, bcntA);
    scanA<<<1, 64, 0, stream>>>(bcntA, regBase, curA);
    scatterA<<<NBA, 256, 0, stream>>>((const int4*)src, (const int4*)dst, curA, tmp);
    histB<<<NBB, 256, 0, stream>>>(tmp, regBase, cellCnt, deg);
    scanB<<<ST, 256, 0, stream>>>(regBase, cellCnt, cellCur);
    scatterB<<<NBB, 256, 0, stream>>>(tmp, regBase, cellCur, ebuf);
    disz<<<(NN + 255) / 256, 256, 0, stream>>>(deg, x0, dis, z0);

    float* zbuf[2] = {z0, z1};
    for (int i = 0; i < 49; i++) {
        int act;
        if (i == 0)            act = 0;
        else if (i == 48)      act = 4;
        else if (i % 10 == 1)  act = 2;                 // leaky {1,11,21,31,41}
        else if (i % 10 == 4)  act = 3;                 // sigmoid {4,14,24,34,44}
        else                   act = 1;                 // relu
        accum<<<NBACC, 512, 0, stream>>>(ebuf, regBase, zbuf[i & 1], hglob);
        finalize<<<(NN + 255) / 256, 256, 0, stream>>>(hglob, zbuf[i & 1], dis, x0, w,
                                                       i, act, zbuf[(i + 1) & 1], out);
    }
}

// Round 5
// 5163.076 us; speedup vs baseline: 1.0558x; 1.0558x over previous
//
#include <hip/hip_runtime.h>
#include <math.h>

#define NN 500000
#define NE 16000000
#define ST 62                    // supertiles: dst>>13 (8192 dst nodes each)
#define STB 8192
#define NG 489                   // src cells: src>>10 (1024 srcs)
#define PBA 16384                // edges per phase-A block
#define NBA ((NE + PBA - 1) / PBA)        // 977
#define SUBB 8                   // histB/scatterB chunks per supertile
#define GRID_B (8 * 64)          // 512: x=bid&7 (XCD class), y=bid>>3: st=x+8*(y&7), chunk=y>>3
#define SORT_CH 16               // sortC cell-chunks per supertile
#define GRID_C (8 * 128)         // 1024
#define CHUNKS 8                 // accum chunks per supertile
#define GRID_ACC (8 * 64)        // 512
#define CELL_CAP 1024            // cell edges: mean 536, sigma 23 -> +21 sigma

// ---------- phase A1: histogram by dst supertile ----------
__global__ __launch_bounds__(256) void histA(const int4* __restrict__ dst4,
                                             int* __restrict__ bcntA) {
    __shared__ int lh[ST];
    if (threadIdx.x < ST) lh[threadIdx.x] = 0;
    __syncthreads();
    long base4 = (long)blockIdx.x * (PBA / 4);
    for (int k = 0; k < PBA / 4; k += 256) {
        long i4 = base4 + k + threadIdx.x;
        if (i4 < NE / 4) {
            int4 d = dst4[i4];
            atomicAdd(&lh[d.x >> 13], 1);
            atomicAdd(&lh[d.y >> 13], 1);
            atomicAdd(&lh[d.z >> 13], 1);
            atomicAdd(&lh[d.w >> 13], 1);
        }
    }
    __syncthreads();
    if (threadIdx.x < ST) {
        int c = lh[threadIdx.x];
        if (c) atomicAdd(&bcntA[threadIdx.x], c);
    }
}

// ---------- phase A2: scan 62 counts (one wave) ----------
__global__ void scanA(const int* __restrict__ bcntA, int* __restrict__ regBase,
                      int* __restrict__ curA) {
    int i = threadIdx.x;                          // 64 threads
    int v = (i < ST) ? bcntA[i] : 0;
    int incl = v;
    for (int off = 1; off < 64; off <<= 1) {
        int t = __shfl_up(incl, off);
        if (i >= off) incl += t;
    }
    if (i < ST) { regBase[i] = incl - v; curA[i] = incl - v; }
    if (i == 63) regBase[ST] = incl;
}

// ---------- phase A3: scatter into supertile regions ----------
// tmp[pos] = (dst&8191)<<19 | src
__global__ __launch_bounds__(256) void scatterA(const int4* __restrict__ src4,
                                                const int4* __restrict__ dst4,
                                                int* __restrict__ curA,
                                                unsigned* __restrict__ tmp) {
    __shared__ int lh[ST];
    if (threadIdx.x < ST) lh[threadIdx.x] = 0;
    __syncthreads();
    long base4 = (long)blockIdx.x * (PBA / 4);
    for (int k = 0; k < PBA / 4; k += 256) {
        long i4 = base4 + k + threadIdx.x;
        if (i4 < NE / 4) {
            int4 d = dst4[i4];
            atomicAdd(&lh[d.x >> 13], 1);
            atomicAdd(&lh[d.y >> 13], 1);
            atomicAdd(&lh[d.z >> 13], 1);
            atomicAdd(&lh[d.w >> 13], 1);
        }
    }
    __syncthreads();
    if (threadIdx.x < ST) {
        int c = lh[threadIdx.x];
        if (c) lh[threadIdx.x] = atomicAdd(&curA[threadIdx.x], c);
    }
    __syncthreads();
    for (int k = 0; k < PBA / 4; k += 256) {
        long i4 = base4 + k + threadIdx.x;
        if (i4 < NE / 4) {
            int4 d = dst4[i4];
            int4 s = src4[i4];
            int p;
            p = atomicAdd(&lh[d.x >> 13], 1); tmp[p] = ((unsigned)(d.x & 8191) << 19) | (unsigned)s.x;
            p = atomicAdd(&lh[d.y >> 13], 1); tmp[p] = ((unsigned)(d.y & 8191) << 19) | (unsigned)s.y;
            p = atomicAdd(&lh[d.z >> 13], 1); tmp[p] = ((unsigned)(d.z & 8191) << 19) | (unsigned)s.z;
            p = atomicAdd(&lh[d.w >> 13], 1); tmp[p] = ((unsigned)(d.w & 8191) << 19) | (unsigned)s.w;
        }
    }
}

// ---------- phase B1: per-(supertile, src-cell) histogram + node degree ----------
__global__ __launch_bounds__(256) void histB(const unsigned* __restrict__ tmp,
                                             const int* __restrict__ regBase,
                                             int* __restrict__ cellCnt,
                                             int* __restrict__ deg) {
    __shared__ int gh[NG];
    __shared__ int dh[STB];
    int x = blockIdx.x & 7, y = blockIdx.x >> 3;
    int st = x + 8 * (y & 7), sb = y >> 3;        // sb in [0,8)
    if (st >= ST) return;
    int base = regBase[st];
    int len = regBase[st + 1] - base;
    int beg = base + (int)((long)len * sb / SUBB);
    int end = base + (int)((long)len * (sb + 1) / SUBB);
    for (int i = threadIdx.x; i < NG; i += 256) gh[i] = 0;
    for (int i = threadIdx.x; i < STB; i += 256) dh[i] = 0;
    __syncthreads();
    for (int i = beg + threadIdx.x; i < end; i += 256) {
        unsigned e = tmp[i];
        atomicAdd(&gh[(e & 0x7FFFFu) >> 10], 1);
        atomicAdd(&dh[e >> 19], 1);
    }
    __syncthreads();
    for (int i = threadIdx.x; i < NG; i += 256) {
        int c = gh[i];
        if (c) atomicAdd(&cellCnt[st * NG + i], c);
    }
    for (int i = threadIdx.x; i < STB; i += 256) {
        int c = dh[i];
        if (c) atomicAdd(&deg[st * STB + i], c);
    }
}

// ---------- phase B2: per-supertile scan of 489 cell counts ----------
__global__ __launch_bounds__(256) void scanB(const int* __restrict__ regBase,
                                             const int* __restrict__ cellCnt,
                                             int* __restrict__ cellBase,
                                             int* __restrict__ cellCur) {
    __shared__ int sh[256];
    __shared__ int carry_sh;
    int st = blockIdx.x;
    if (threadIdx.x == 0) carry_sh = regBase[st];
    __syncthreads();
    for (int base = 0; base < NG; base += 256) {
        int i = base + threadIdx.x;
        int v = (i < NG) ? cellCnt[st * NG + i] : 0;
        sh[threadIdx.x] = v;
        __syncthreads();
        for (int off = 1; off < 256; off <<= 1) {
            int t = (threadIdx.x >= off) ? sh[threadIdx.x - off] : 0;
            __syncthreads();
            sh[threadIdx.x] += t;
            __syncthreads();
        }
        int incl = sh[threadIdx.x];
        int c = carry_sh;
        __syncthreads();
        if (i < NG) {
            int ex = c + incl - v;
            cellBase[st * NG + i] = ex;
            cellCur[st * NG + i] = ex;
        }
        if (threadIdx.x == 255) carry_sh = c + incl;
        __syncthreads();
    }
}

// ---------- phase B3: scatter within supertile by src-cell (XCD-pinned) ----------
__global__ __launch_bounds__(512) void scatterB(const unsigned* __restrict__ tmp,
                                                const int* __restrict__ regBase,
                                                int* __restrict__ cellCur,
                                                unsigned* __restrict__ ebuf) {
    __shared__ int gh[NG];
    int x = blockIdx.x & 7, y = blockIdx.x >> 3;
    int st = x + 8 * (y & 7), sb = y >> 3;
    if (st >= ST) return;
    int base = regBase[st];
    int len = regBase[st + 1] - base;
    int beg = base + (int)((long)len * sb / SUBB);
    int end = base + (int)((long)len * (sb + 1) / SUBB);
    for (int i = threadIdx.x; i < NG; i += 512) gh[i] = 0;
    __syncthreads();
    for (int i = beg + threadIdx.x; i < end; i += 512)
        atomicAdd(&gh[(tmp[i] & 0x7FFFFu) >> 10], 1);
    __syncthreads();
    for (int i = threadIdx.x; i < NG; i += 512) {
        int c = gh[i];
        if (c) gh[i] = atomicAdd(&cellCur[st * NG + i], c);
    }
    __syncthreads();
    for (int i = beg + threadIdx.x; i < end; i += 512) {
        unsigned e = tmp[i];
        int pos = atomicAdd(&gh[(e & 0x7FFFFu) >> 10], 1);
        ebuf[pos] = e;
    }
}

// ---------- phase C: in-place per-cell counting sort by src (full sort) ----------
__global__ __launch_bounds__(256) void sortC(const int* __restrict__ cellBase,
                                             const int* __restrict__ regBase,
                                             unsigned* __restrict__ ebuf) {
    __shared__ unsigned eds[CELL_CAP];
    __shared__ unsigned outb[CELL_CAP];
    __shared__ int cnt[1024];
    __shared__ int scn[256];
    int x = blockIdx.x & 7, y = blockIdx.x >> 3;
    int st = x + 8 * (y & 7), q = y >> 3;         // q in [0,16)
    if (st >= ST) return;
    int c0 = (q * NG) / SORT_CH, c1 = ((q + 1) * NG) / SORT_CH;
    for (int c = c0; c < c1; c++) {
        int beg = cellBase[st * NG + c];
        int end = (c == NG - 1) ? regBase[st + 1] : cellBase[st * NG + c + 1];
        int n = end - beg;
        if (n > CELL_CAP) n = CELL_CAP;           // statistically impossible
        for (int i = threadIdx.x; i < n; i += 256) eds[i] = ebuf[beg + i];
        for (int i = threadIdx.x; i < 1024; i += 256) cnt[i] = 0;
        __syncthreads();
        for (int i = threadIdx.x; i < n; i += 256) atomicAdd(&cnt[eds[i] & 1023], 1);
        __syncthreads();
        int b0 = cnt[4 * threadIdx.x], b1 = cnt[4 * threadIdx.x + 1];
        int b2 = cnt[4 * threadIdx.x + 2], b3 = cnt[4 * threadIdx.x + 3];
        int s = b0 + b1 + b2 + b3;
        scn[threadIdx.x] = s;
        __syncthreads();
        for (int off = 1; off < 256; off <<= 1) {
            int t = (threadIdx.x >= off) ? scn[threadIdx.x - off] : 0;
            __syncthreads();
            scn[threadIdx.x] += t;
            __syncthreads();
        }
        int ex = scn[threadIdx.x] - s;
        cnt[4 * threadIdx.x] = ex;
        cnt[4 * threadIdx.x + 1] = ex + b0;
        cnt[4 * threadIdx.x + 2] = ex + b0 + b1;
        cnt[4 * threadIdx.x + 3] = ex + b0 + b1 + b2;
        __syncthreads();
        for (int i = threadIdx.x; i < n; i += 256) {
            unsigned e = eds[i];
            int pos = atomicAdd(&cnt[e & 1023], 1);
            outb[pos] = e;
        }
        __syncthreads();
        for (int i = threadIdx.x; i < n; i += 256) ebuf[beg + i] = outb[i];
        __syncthreads();
    }
}

// ---------- dis + z0 ----------
__global__ void disz(const int* __restrict__ deg, const float* __restrict__ x0,
                     float* __restrict__ dis, float* __restrict__ z0) {
    int v = blockIdx.x * 256 + threadIdx.x;
    if (v < NN) {
        float f = rsqrtf((float)(deg[v] + 1));     // +1 self loop
        dis[v] = f;
        z0[v] = x0[v] * f;
    }
}

// ---------- per-layer: accumulate (src-sorted gather -> LDS tile -> partial) ----------
__global__ __launch_bounds__(512) void accum(const unsigned* __restrict__ ebuf,
                                             const int* __restrict__ regBase,
                                             const float* __restrict__ zin,
                                             float* __restrict__ partial) {
    __shared__ float h[STB];
    int x = blockIdx.x & 7, y = blockIdx.x >> 3;
    int st = x + 8 * (y & 7), c = y >> 3;          // c in [0,8)
    if (st >= ST) return;
    int base = regBase[st];
    int len = regBase[st + 1] - base;
    int beg = base + (int)((long)len * c / CHUNKS);
    int end = base + (int)((long)len * (c + 1) / CHUNKS);
    for (int j = threadIdx.x; j < STB; j += 512) h[j] = 0.f;
    __syncthreads();
    int beg4 = (beg + 3) & ~3;
    if (beg4 > end) beg4 = end;
    int end4 = end & ~3;
    if (end4 < beg4) end4 = beg4;
    for (int i = beg + threadIdx.x; i < beg4; i += 512) {
        unsigned e = ebuf[i];
        atomicAdd(&h[e >> 19], zin[e & 0x7FFFFu]);
    }
    const uint4* eb4 = (const uint4*)ebuf;
    for (int i4 = beg4 / 4 + threadIdx.x; i4 < end4 / 4; i4 += 512) {
        uint4 e = eb4[i4];
        atomicAdd(&h[e.x >> 19], zin[e.x & 0x7FFFFu]);
        atomicAdd(&h[e.y >> 19], zin[e.y & 0x7FFFFu]);
        atomicAdd(&h[e.z >> 19], zin[e.z & 0x7FFFFu]);
        atomicAdd(&h[e.w >> 19], zin[e.w & 0x7FFFFu]);
    }
    for (int i = end4 + threadIdx.x; i < end; i += 512) {
        unsigned e = ebuf[i];
        atomicAdd(&h[e >> 19], zin[e & 0x7FFFFu]);
    }
    __syncthreads();
    float* pt = partial + (size_t)c * (ST * STB) + st * STB;
    for (int j = threadIdx.x; j < STB; j += 512) pt[j] = h[j];
}

// ---------- per-layer: finalize (sum partials, self-loop, activation) ----------
// act: 0=none 1=relu 2=leaky(0.01) 3=sigmoid 4=final(n*sigmoid -> int)
__global__ __launch_bounds__(256) void finalize(const float* __restrict__ partial,
                                                const float* __restrict__ zin,
                                                const float* __restrict__ dis,
                                                const float* __restrict__ x0,
                                                const float* __restrict__ w,
                                                int li, int act,
                                                float* __restrict__ zout,
                                                int* __restrict__ out) {
    int v = blockIdx.x * 256 + threadIdx.x;
    if (v >= NN) return;
    float hv = 0.f;
    #pragma unroll
    for (int c = 0; c < CHUNKS; c++) hv += partial[(size_t)c * (ST * STB) + v];
    float s = hv + zin[v];                          // + self loop
    float hh = dis[v] * s;
    float comb = 0.7f * hh + 0.3f * x0[v];
    float y = comb * w[li];
    if (act == 4) {
        float sg = 1.f / (1.f + expf(-y));
        out[v] = (int)(500000.f * sg);
        return;
    }
    float r;
    if (act == 0)      r = y;
    else if (act == 1) r = fmaxf(y, 0.f);
    else if (act == 2) r = (y > 0.f) ? y : 0.01f * y;
    else               r = 1.f / (1.f + expf(-y));  // sigmoid
    zout[v] = dis[v] * r;
}

// ---------- launch ----------
extern "C" void kernel_launch(void* const* d_in, const int* in_sizes, int n_in,
                              void* d_out, int out_size, void* d_ws, size_t ws_size,
                              hipStream_t stream) {
    const float* x0  = (const float*)d_in[0];
    const float* w   = (const float*)d_in[1];
    const int*   adj = (const int*)d_in[2];          // int32 (jax demotes int64)
    const int*   src = adj;
    const int*   dst = adj + NE;
    int* out = (int*)d_out;

    uintptr_t p = (uintptr_t)d_ws;
    auto alloc = [&](size_t bytes) -> void* {
        p = (p + 255) & ~(uintptr_t)255;
        void* r = (void*)p;
        p += bytes;
        return r;
    };
    float*    dis      = (float*)alloc((size_t)NN * 4);
    float*    z0       = (float*)alloc((size_t)NN * 4);
    float*    z1       = (float*)alloc((size_t)NN * 4);
    int*      deg      = (int*)alloc((size_t)ST * STB * 4);
    float*    partial  = (float*)alloc((size_t)CHUNKS * ST * STB * 4);
    int*      bcntA    = (int*)alloc((size_t)ST * 4);
    int*      regBase  = (int*)alloc((size_t)(ST + 1) * 4);
    int*      curA     = (int*)alloc((size_t)ST * 4);
    int*      cellCnt  = (int*)alloc((size_t)ST * NG * 4);
    int*      cellBase = (int*)alloc((size_t)ST * NG * 4);
    int*      cellCur  = (int*)alloc((size_t)ST * NG * 4);
    unsigned* tmp      = (unsigned*)alloc((size_t)NE * 4);
    unsigned* ebuf     = (unsigned*)alloc((size_t)NE * 4);
    (void)ws_size;

    hipMemsetAsync(bcntA, 0, (size_t)ST * 4, stream);
    hipMemsetAsync(cellCnt, 0, (size_t)ST * NG * 4, stream);
    hipMemsetAsync(deg, 0, (size_t)ST * STB * 4, stream);

    histA<<<NBA, 256, 0, stream>>>((const int4*)dst, bcntA);
    scanA<<<1, 64, 0, stream>>>(bcntA, regBase, curA);
    scatterA<<<NBA, 256, 0, stream>>>((const int4*)src, (const int4*)dst, curA, tmp);
    histB<<<GRID_B, 256, 0, stream>>>(tmp, regBase, cellCnt, deg);
    scanB<<<ST, 256, 0, stream>>>(regBase, cellCnt, cellBase, cellCur);
    scatterB<<<GRID_B, 512, 0, stream>>>(tmp, regBase, cellCur, ebuf);
    sortC<<<GRID_C, 256, 0, stream>>>(cellBase, regBase, ebuf);
    disz<<<(NN + 255) / 256, 256, 0, stream>>>(deg, x0, dis, z0);

    float* zbuf[2] = {z0, z1};
    for (int i = 0; i < 49; i++) {
        int act;
        if (i == 0)            act = 0;
        else if (i == 48)      act = 4;
        else if (i % 10 == 1)  act = 2;                 // leaky {1,11,21,31,41}
        else if (i % 10 == 4)  act = 3;                 // sigmoid {4,14,24,34,44}
        else                   act = 1;                 // relu
        accum<<<GRID_ACC, 512, 0, stream>>>(ebuf, regBase, zbuf[i & 1], partial);
        finalize<<<(NN + 255) / 256, 256, 0, stream>>>(partial, zbuf[i & 1], dis, x0, w,
                                                       i, act, zbuf[(i + 1) & 1], out);
    }
}